// Round 1
// baseline (34.149 us; speedup 1.0000x reference)
//
#include <hip/hip_runtime.h>

#define TPB 256
#define ROWLEN 16000          // T
#define NROWS 1280            // B*C
#define NCHUNK 250            // active scan threads (250 * 64 = 16000)
#define SEGS 62               // full 1KB wave segments (62*64 slots = 3968 of 4000)
#define SCAN_OFF 16000        // float offset of scan array in LDS

typedef float f32x4 __attribute__((ext_vector_type(4)));

// involutive 16B-slot swizzle (st_16x32 style): spreads 256B-strided lane
// accesses across all 8 bank-quads
__device__ __forceinline__ unsigned swz(unsigned s) { return s ^ ((s >> 4) & 7u); }

__global__ __launch_bounds__(TPB) void ema_kernel(const float* __restrict__ x,
                                                  const float* __restrict__ wts,
                                                  float* __restrict__ y) {
  __shared__ float lds[16256];            // 16000 data + 256 scan = 65024 B
  const int row  = blockIdx.x;            // 0..1279  (row = b*80 + c)
  const int c    = row % 80;
  const int tid  = threadIdx.x;
  const int lane = tid & 63;
  const int wv   = tid >> 6;

  const float* __restrict__ xr = x + (size_t)row * ROWLEN;
  float* __restrict__ yr       = y + (size_t)row * ROWLEN;

  float w = wts[c];
  w = fminf(fmaxf(w, 0.f), 1.f);
  const float d = 1.f - w;

  // ---- stage in: global -> LDS; linear LDS dest, pre-swizzled global src ----
  for (int seg = wv; seg < SEGS; seg += 4) {
    unsigned p = (unsigned)(seg * 64 + lane);   // phys slot this lane fills
    unsigned g = swz(p);                        // logical 16B chunk to fetch
    __builtin_amdgcn_global_load_lds(
        (const __attribute__((address_space(1))) void*)(xr + g * 4),
        (__attribute__((address_space(3))) void*)(&lds[seg * 256]),
        16, 0, 0);
  }
  // tail: logical words 15872..15999 (32 slots), scalar path
  if (tid < 128) {
    int wrd = 15872 + tid;
    unsigned p = swz((unsigned)(wrd >> 2));
    lds[p * 4 + (wrd & 3)] = xr[wrd];
  }
  __syncthreads();

  const float init = lds[0];   // logical word 0 == phys word 0

  // ---- phase 1: chunk -> regs (swizzled b128 reads), local contribution L ----
  f32x4 xv[16];
  float L = 0.f;
  if (tid < NCHUNK) {
#pragma unroll
    for (int k = 0; k < 16; ++k) {
      unsigned p = swz((unsigned)(tid * 16 + k));   // == (tid*16+k) ^ (tid&7)
      xv[k] = *(const f32x4*)&lds[p * 4];
    }
#pragma unroll
    for (int k = 0; k < 16; ++k)
#pragma unroll
      for (int j = 0; j < 4; ++j)
        L = w * xv[k][j] + d * L;
  }
  // chunk decay D = d^64 via 6 squarings
  float D = d * d; D = D * D; D = D * D; D = D * D; D = D * D; D = D * D;

  // ---- block scan: S[t] = L_t + D*S[t-1] (decayed inclusive, in-place H-S) ----
  float* S = &lds[SCAN_OFF];
  float s = (tid < NCHUNK) ? L : 0.f;
  S[tid] = s;
  __syncthreads();
  float Dp = D;
  for (int step = 1; step < TPB; step <<= 1) {
    float add = (tid >= step) ? S[tid - step] : 0.f;
    __syncthreads();
    s = s + Dp * add;
    S[tid] = s;
    Dp = Dp * Dp;
    __syncthreads();
  }

  // ---- phase 3: replay exact sequential recurrence per chunk ----
  if (tid < NCHUNK) {
    float acc = powf(D, (float)tid) * init;     // D^tid * init
    if (tid > 0) acc += S[tid - 1];
#pragma unroll
    for (int k = 0; k < 16; ++k) {
      f32x4 yv;
#pragma unroll
      for (int j = 0; j < 4; ++j) {
        acc = w * xv[k][j] + d * acc;           // same op order as reference
        yv[j] = acc;
      }
      unsigned p = swz((unsigned)(tid * 16 + k));
      *(f32x4*)&lds[p * 4] = yv;
    }
  }
  __syncthreads();

  // ---- stage out: linear LDS reads, permuted (dense) global stores ----
  for (int seg = wv; seg < SEGS; seg += 4) {
    unsigned p = (unsigned)(seg * 64 + lane);
    unsigned g = swz(p);
    f32x4 v = *(const f32x4*)&lds[p * 4];
    *(f32x4*)(yr + g * 4) = v;
  }
  if (tid < 128) {
    int wrd = 15872 + tid;
    unsigned p = swz((unsigned)(wrd >> 2));
    yr[wrd] = lds[p * 4 + (wrd & 3)];
  }
}

extern "C" void kernel_launch(void* const* d_in, const int* in_sizes, int n_in,
                              void* d_out, int out_size, void* d_ws, size_t ws_size,
                              hipStream_t stream) {
  const float* x   = (const float*)d_in[0];
  const float* wts = (const float*)d_in[1];
  float* y         = (float*)d_out;
  ema_kernel<<<NROWS, TPB, 0, stream>>>(x, wts, y);
}